// Round 1
// baseline (695.679 us; speedup 1.0000x reference)
//
#include <hip/hip_runtime.h>
#include <math.h>

// ---- problem constants (match reference) ----
#define WAV_N     262144
#define HOP       128
#define MIN_WIN   16699
#define N_FFT     65536
#define LEFT      24418            // (N_FFT - MIN_WIN)/2
#define T_FRAMES  2049             // 1 + WAV_N/HOP
#define N_BINS    96
#define N_CQCC    20
#define F_COMP    192              // 96 bins x {lo,hi}

#define XS_VALID  278843           // 2048*128 + 16699
#define XS_ALLOC  282880           // padded so out-of-range frames read in-bounds

// ---- main-kernel tiling ----
#define T_TILE    32
#define F_TILE    32
#define KSPLIT    8
#define KCHUNK    2088             // ceil(16699/8)
#define KC        64
#define NSUB      33               // ceil(2088/64)

// ---- workspace layout (bytes) ----
#define WS_XS     0
#define WS_B      1131520          // XS_ALLOC*4
#define WS_S      26781184         // WS_B + 16699*384*4
#define WS_CQ     29928448         // WS_S + 2049*384*4
#define WS_MEAN   30092544
#define WS_INV    30092624

// xs[m] = reflect-padded wav at (LEFT + m), i.e. frame t sample j = xs[t*HOP + j]
__global__ void k_init_xs(const float* __restrict__ wav, float* __restrict__ xs) {
    int m = blockIdx.x * blockDim.x + threadIdx.x;
    if (m >= XS_ALLOC) return;
    float v = 0.0f;
    if (m < XS_VALID) {
        int j = m - 8350;                    // m + LEFT - N_FFT/2
        if (j < 0) j = -j;                   // left reflect
        if (j >= WAV_N) j = 2 * WAV_N - 2 - j; // right reflect
        v = wav[j];
    }
    xs[m] = v;
}

// B[k][c][0] = hann[k]*cos(phi), B[k][c][1] = -hann[k]*sin(phi)
// phi = 2*pi*((fi_c*(LEFT+k)) mod 65536)/65536, fi_c = integer FFT bin for comp c
__global__ void k_init_B(float* __restrict__ B) {
    int gid = blockIdx.x * blockDim.x + threadIdx.x;
    if (gid >= MIN_WIN * F_COMP) return;
    int k = gid / F_COMP;
    int c = gid - k * F_COMP;
    int b = c >> 1;
    int hi = c & 1;
    // replicate reference f32 arithmetic for the floor() decision
    float e    = (float)b / 24.0f;
    float fb   = 32.7f * exp2f(e);
    float idxf = fb / 8000.0f * 32768.0f;
    int   il   = (int)idxf;
    int   fi   = il + hi;
    unsigned p = ((unsigned)fi * (unsigned)(LEFT + k)) & 65535u;
    double ang = (double)p * (2.0 * M_PI / 65536.0);
    double sn, cs;
    sincos(ang, &sn, &cs);
    double hw = 0.5 - 0.5 * cos(2.0 * M_PI * (double)k / (double)MIN_WIN);
    B[gid * 2 + 0] = (float)(hw * cs);
    B[gid * 2 + 1] = (float)(-hw * sn);
}

// S[t][c][{re,im}] += sum over this block's K-chunk of xs[t*HOP+k]*B[k][c][:]
__global__ __launch_bounds__(256) void k_main(const float* __restrict__ xs,
                                              const float* __restrict__ B,
                                              float* __restrict__ S) {
    __shared__ float A_lds[KC * 33];                 // [kl][tl], pad 33 vs bank conflicts
    __shared__ __align__(16) float B_lds[KC * 64];   // [kl][32 comps x {re,im}]

    int tid = threadIdx.x;
    int t0 = blockIdx.x * T_TILE;
    int f0 = blockIdx.y * F_TILE;
    int kstart = blockIdx.z * KCHUNK;
    int kend = min(kstart + KCHUNK, MIN_WIN);

    int ft  = tid & 31;        // component within tile
    int tt4 = (tid >> 5) * 4;  // first of this thread's 4 frames

    int kl_a = tid & 63;       // A-staging: k within sub-chunk
    int tg   = tid >> 6;       // A-staging: frame group (0..3)

    float accr[4] = {0.f, 0.f, 0.f, 0.f};
    float acci[4] = {0.f, 0.f, 0.f, 0.f};

    for (int sc = 0; sc < NSUB; ++sc) {
        int ks = kstart + sc * KC;
        __syncthreads();
        // stage A: A_lds[kl][tl] = xs[(t0+tl)*HOP + ks + kl]  (coalesced in kl)
        {
            int base = (t0 + tg * 8) * HOP + ks + kl_a;
            #pragma unroll
            for (int j = 0; j < 8; ++j)
                A_lds[kl_a * 33 + tg * 8 + j] = xs[base + j * HOP];
        }
        // stage B: 64 contiguous floats per k-row (32 comps x re,im), float4 loads
        {
            #pragma unroll
            for (int i = 0; i < 4; ++i) {
                int o = i * 256 + tid;             // float4 slot
                int kl = o >> 4;
                int inner = (o & 15) * 4;
                int k = ks + kl;
                float4 v = make_float4(0.f, 0.f, 0.f, 0.f);
                if (k < kend)
                    v = *(const float4*)(B + (size_t)k * 384 + f0 * 2 + inner);
                ((float4*)B_lds)[o] = v;
            }
        }
        __syncthreads();
        #pragma unroll 8
        for (int kl = 0; kl < KC; ++kl) {
            float2 bw = ((const float2*)B_lds)[kl * 32 + ft];
            const float* ap = &A_lds[kl * 33 + tt4];
            float a0 = ap[0], a1 = ap[1], a2 = ap[2], a3 = ap[3];
            accr[0] = fmaf(a0, bw.x, accr[0]); acci[0] = fmaf(a0, bw.y, acci[0]);
            accr[1] = fmaf(a1, bw.x, accr[1]); acci[1] = fmaf(a1, bw.y, acci[1]);
            accr[2] = fmaf(a2, bw.x, accr[2]); acci[2] = fmaf(a2, bw.y, acci[2]);
            accr[3] = fmaf(a3, bw.x, accr[3]); acci[3] = fmaf(a3, bw.y, acci[3]);
        }
    }
    #pragma unroll
    for (int i = 0; i < 4; ++i) {
        int t = t0 + tt4 + i;
        if (t < T_FRAMES) {
            atomicAdd(&S[((size_t)t * F_COMP + f0 + ft) * 2 + 0], accr[i]);
            atomicAdd(&S[((size_t)t * F_COMP + f0 + ft) * 2 + 1], acci[i]);
        }
    }
}

// power -> linear interp at CQT freqs -> log -> DCT (20x96)
__global__ void k_cqt(const float* __restrict__ S, float* __restrict__ cq) {
    __shared__ float lg[N_BINS];
    int t = blockIdx.x;
    int tid = threadIdx.x;
    if (tid < N_BINS) {
        float4 v = *(const float4*)(S + (size_t)t * 384 + tid * 4); // re_lo,im_lo,re_hi,im_hi
        float pl = v.x * v.x + v.y * v.y;
        float ph = v.z * v.z + v.w * v.w;
        float e    = (float)tid / 24.0f;
        float fb   = 32.7f * exp2f(e);
        float idxf = fb / 8000.0f * 32768.0f;
        float alpha = idxf - (float)((int)idxf);
        float p = (1.0f - alpha) * pl + alpha * ph;
        lg[tid] = logf(fmaxf(p, 1e-8f));
    }
    __syncthreads();
    if (tid < N_CQCC) {
        float s = 0.0f;
        for (int b = 0; b < N_BINS; ++b) {
            float arg = (float)M_PI * (float)(tid * (2 * b + 1)) / 192.0f;
            s += cosf(arg) * lg[b];
        }
        cq[t * N_CQCC + tid] = s;
    }
}

// per-coefficient mean / 1/(std+1e-8) over time, ddof=1, fp64 accumulation
__global__ void k_stats(const float* __restrict__ cq, float* __restrict__ mean,
                        float* __restrict__ inv) {
    int k = blockIdx.x;
    int tid = threadIdx.x;
    double s = 0.0, sq = 0.0;
    for (int t = tid; t < T_FRAMES; t += 256) {
        double v = (double)cq[t * N_CQCC + k];
        s += v; sq += v * v;
    }
    #pragma unroll
    for (int off = 32; off > 0; off >>= 1) {
        s  += __shfl_down(s, off);
        sq += __shfl_down(sq, off);
    }
    __shared__ double rs[4], rq[4];
    int w = tid >> 6;
    if ((tid & 63) == 0) { rs[w] = s; rq[w] = sq; }
    __syncthreads();
    if (tid == 0) {
        s  = rs[0] + rs[1] + rs[2] + rs[3];
        sq = rq[0] + rq[1] + rq[2] + rq[3];
        double m = s / (double)T_FRAMES;
        double var = (sq - s * m) / (double)(T_FRAMES - 1);
        double sd = sqrt(var > 0.0 ? var : 0.0);
        mean[k] = (float)m;
        inv[k]  = (float)(1.0 / (sd + 1e-8));
    }
}

__device__ __forceinline__ int clampT(int v) {
    return v < 0 ? 0 : (v > T_FRAMES - 1 ? T_FRAMES - 1 : v);
}

// normalize + delta + delta-delta, write [T, 60]
__global__ void k_final(const float* __restrict__ cq, const float* __restrict__ mean,
                        const float* __restrict__ inv, float* __restrict__ out) {
    int gid = blockIdx.x * blockDim.x + threadIdx.x;
    if (gid >= T_FRAMES * N_CQCC) return;
    int t = gid / N_CQCC;
    int k = gid - t * N_CQCC;
    float m = mean[k], iv = inv[k];
    float cv[9];
    #pragma unroll
    for (int j = 0; j < 9; ++j)
        cv[j] = (cq[clampT(t + j - 4) * N_CQCC + k] - m) * iv;
    float dv[5];
    #pragma unroll
    for (int o = -2; o <= 2; ++o) {
        int p = clampT(t + o);
        int h1 = clampT(p + 1) - t, l1 = clampT(p - 1) - t;
        int h2 = clampT(p + 2) - t, l2 = clampT(p - 2) - t;
        dv[o + 2] = ((cv[h1 + 4] - cv[l1 + 4]) + 2.0f * (cv[h2 + 4] - cv[l2 + 4])) * 0.1f;
    }
    out[t * 60 + k]      = cv[4];
    out[t * 60 + 20 + k] = dv[2];
    out[t * 60 + 40 + k] = (dv[3] - dv[1] + 2.0f * (dv[4] - dv[0])) * 0.1f;
}

extern "C" void kernel_launch(void* const* d_in, const int* in_sizes, int n_in,
                              void* d_out, int out_size, void* d_ws, size_t ws_size,
                              hipStream_t stream) {
    const float* wav = (const float*)d_in[0];
    float* out = (float*)d_out;
    char* ws = (char*)d_ws;
    float* xs   = (float*)(ws + WS_XS);
    float* B    = (float*)(ws + WS_B);
    float* S    = (float*)(ws + WS_S);
    float* cq   = (float*)(ws + WS_CQ);
    float* mean = (float*)(ws + WS_MEAN);
    float* inv  = (float*)(ws + WS_INV);

    k_init_xs<<<(XS_ALLOC + 255) / 256, 256, 0, stream>>>(wav, xs);
    k_init_B<<<(MIN_WIN * F_COMP + 255) / 256, 256, 0, stream>>>(B);
    hipMemsetAsync(S, 0, (size_t)T_FRAMES * F_COMP * 2 * sizeof(float), stream);
    k_main<<<dim3((T_FRAMES + T_TILE - 1) / T_TILE, F_COMP / F_TILE, KSPLIT),
             256, 0, stream>>>(xs, B, S);
    k_cqt<<<T_FRAMES, 128, 0, stream>>>(S, cq);
    k_stats<<<N_CQCC, 256, 0, stream>>>(cq, mean, inv);
    k_final<<<(T_FRAMES * N_CQCC + 255) / 256, 256, 0, stream>>>(cq, mean, inv, out);
}

// Round 2
// 151.131 us; speedup vs baseline: 4.6032x; 4.6032x over previous
//
#include <hip/hip_runtime.h>
#include <math.h>

// ---- problem constants (match reference) ----
#define WAV_N     262144
#define HOP       128
#define MIN_WIN   16699
#define LEFT      24418            // (65536 - 16699)/2
#define T_FRAMES  2049
#define N_BINS    96
#define N_CQCC    20
#define F_COMP    192              // 96 bins x {lo,hi}
#define NF        576              // 192 comps x 3 Hann planes
#define NBLK      2179             // 128-sample chunks covering xs
#define NB64      35               // ceil(2179/64)
#define PARTLEN   59               // 16699 - 130*128
#define FULLBLK   130              // full chunks per window
#define XS_VALID  278843           // 2048*128 + 16699
#define XS_ALLOC  282880

// ---- chunk-matmul tiling ----
#define BT 32
#define FT 32

// ---- workspace layout (bytes) ----
#define WS_XS   0                  // 1,131,520
#define WS_E    1131520            // 589,824
#define WS_QF   1721344            // 10,040,832 (Qfull, overwritten in-place by G)
#define WS_QP   11762176           // 10,040,832
#define WS_BS   21803008           // 322,560
#define WS_OF   22125568           // 322,560
#define WS_S    22448128           // 3,147,264
#define WS_CQ   25595392           // 163,920
#define WS_MEAN 25759360
#define WS_INV  25759488

// xs[m] = reflect-padded wav at (LEFT + m); frame t sample k = xs[t*128 + k]
__global__ void k_init_xs(const float* __restrict__ wav, float* __restrict__ xs) {
    int m = blockIdx.x * blockDim.x + threadIdx.x;
    if (m >= XS_ALLOC) return;
    float v = 0.0f;
    if (m < XS_VALID) {
        int j = m - 8350;                      // m + LEFT - 32768
        if (j < 0) j = -j;
        if (j >= WAV_N) j = 2 * WAV_N - 2 - j;
        v = wav[j];
    }
    xs[m] = v;
}

// f = plane*192 + c; c = bin*2 + hi; replicate reference f32 arithmetic for floor()
__device__ __forceinline__ void f_to_fi_sigma(int f, int& fi, int& sigma) {
    int plane = f / 192;
    int c = f - plane * 192;
    int bin = c >> 1, hi = c & 1;
    float e    = (float)bin / 24.0f;
    float fb   = 32.7f * exp2f(e);
    float idxf = fb / 8000.0f * 32768.0f;
    fi = (int)idxf + hi;
    sigma = (plane == 0) ? 0 : (plane == 1 ? 1 : -1);
}

// E[j][f] = e^{-i*2*pi*(j*fi/65536 - sigma*j/W)}  (intra-chunk twiddle)
__global__ void k_E(float2* __restrict__ E) {
    int gid = blockIdx.x * blockDim.x + threadIdx.x;
    if (gid >= 128 * NF) return;
    int j = gid / NF, f = gid - j * NF;
    int fi, sg; f_to_fi_sigma(f, fi, sg);
    double fr = (double)((j * fi) & 65535) / 65536.0
              - (double)sg * (double)j / (double)MIN_WIN;
    fr -= rint(fr);
    double sn, cs;
    sincos(2.0 * M_PI * fr, &sn, &cs);
    E[gid] = make_float2((float)cs, (float)(-sn));
}

// Qfull[b][f] = e^{-i w0(b,f)} * sum_{j<128} xs[128b+j]*E[j][f]; Qpart = j<59 version
__global__ __launch_bounds__(256) void k_chunk(const float* __restrict__ xs,
                                               const float2* __restrict__ E,
                                               float2* __restrict__ Qfull,
                                               float2* __restrict__ Qpart) {
    __shared__ float A_lds[128 * 33];          // [j][bl], pad 33
    __shared__ float2 E_lds[128 * FT];         // [j][fl]
    int tid = threadIdx.x;
    int b0 = blockIdx.x * BT;
    int f0 = blockIdx.y * FT;
    {
        const float* src = xs + 128 * b0;      // max read 128*2176+4095 < XS_ALLOC
        #pragma unroll
        for (int i = 0; i < 16; ++i) {
            int m = i * 256 + tid;
            A_lds[(m & 127) * 33 + (m >> 7)] = src[m];
        }
    }
    {
        #pragma unroll
        for (int i = 0; i < 16; ++i) {
            int ii = i * 256 + tid;
            int j = ii >> 5, fl = ii & 31;
            E_lds[ii] = E[j * NF + f0 + fl];
        }
    }
    __syncthreads();

    int ft = tid & 31;          // f within tile
    int bg = tid >> 5;          // b group (0..7), 4 b's each
    float xr[4] = {0,0,0,0}, xi[4] = {0,0,0,0};
    float pxr[4], pxi[4];

    #pragma unroll 4
    for (int j = 0; j < PARTLEN; ++j) {
        float2 ev = E_lds[j * 32 + ft];
        const float* ap = &A_lds[j * 33 + bg * 4];
        #pragma unroll
        for (int i = 0; i < 4; ++i) {
            xr[i] = fmaf(ap[i], ev.x, xr[i]);
            xi[i] = fmaf(ap[i], ev.y, xi[i]);
        }
    }
    #pragma unroll
    for (int i = 0; i < 4; ++i) { pxr[i] = xr[i]; pxi[i] = xi[i]; }
    #pragma unroll 4
    for (int j = PARTLEN; j < 128; ++j) {
        float2 ev = E_lds[j * 32 + ft];
        const float* ap = &A_lds[j * 33 + bg * 4];
        #pragma unroll
        for (int i = 0; i < 4; ++i) {
            xr[i] = fmaf(ap[i], ev.x, xr[i]);
            xi[i] = fmaf(ap[i], ev.y, xi[i]);
        }
    }

    int f = f0 + ft;
    int fi, sg; f_to_fi_sigma(f, fi, sg);
    #pragma unroll
    for (int i = 0; i < 4; ++i) {
        int b = b0 + bg * 4 + i;
        if (b >= NBLK) continue;
        unsigned ph = ((unsigned)fi * (unsigned)(LEFT + 128 * b)) & 65535u;
        float frf = (float)ph * (1.0f / 65536.0f)
                  - (float)sg * (float)((128 * b) % MIN_WIN) * (1.0f / (float)MIN_WIN);
        frf -= rintf(frf);
        float sn, cs;
        __sincosf(6.283185307179586f * frf, &sn, &cs);
        // multiply by e^{-i w0} = (cs, -sn)
        Qfull[b * NF + f] = make_float2(xr[i] * cs + xi[i] * sn,
                                        xi[i] * cs - xr[i] * sn);
        Qpart[b * NF + f] = make_float2(pxr[i] * cs + pxi[i] * sn,
                                        pxi[i] * cs - pxr[i] * sn);
    }
}

// stage 1: per-(f, 64-block) sums of Qfull (fp64)
__global__ void k_scan1(const float2* __restrict__ Qfull, double2* __restrict__ bsum) {
    int gid = blockIdx.x * blockDim.x + threadIdx.x;
    if (gid >= NF * NB64) return;
    int f = gid % NF, blk = gid / NF;
    double sr = 0.0, si = 0.0;
    int bend = min(NBLK, (blk + 1) * 64);
    for (int b = blk * 64; b < bend; ++b) {
        float2 q = Qfull[b * NF + f];
        sr += q.x; si += q.y;
    }
    bsum[blk * NF + f] = make_double2(sr, si);
}

// stage 2: exclusive scan of the 35 block sums per f
__global__ void k_scan2(const double2* __restrict__ bsum, double2* __restrict__ offs) {
    int f = blockIdx.x * blockDim.x + threadIdx.x;
    if (f >= NF) return;
    double sr = 0.0, si = 0.0;
    for (int blk = 0; blk < NB64; ++blk) {
        double2 v = bsum[blk * NF + f];
        offs[blk * NF + f] = make_double2(sr, si);
        sr += v.x; si += v.y;
    }
}

// stage 3: exclusive prefix G over b, in-place over Qfull (read-then-write per element)
__global__ void k_scan3(float2* __restrict__ QG, const double2* __restrict__ offs) {
    int gid = blockIdx.x * blockDim.x + threadIdx.x;
    if (gid >= NF * NB64) return;
    int f = gid % NF, blk = gid / NF;
    double2 o = offs[blk * NF + f];
    double sr = o.x, si = o.y;
    int bend = min(NBLK, (blk + 1) * 64);
    for (int b = blk * 64; b < bend; ++b) {
        float2 q = QG[b * NF + f];
        QG[b * NF + f] = make_float2((float)sr, (float)si);
        sr += q.x; si += q.y;
    }
}

// V_sigma[t,c] = e^{+i tau}(G[t+130]-G[t]+Qpart[t+130]); S = 0.5 V0 - 0.25 V+ - 0.25 V-
__global__ void k_combine(const float2* __restrict__ G, const float2* __restrict__ Qpart,
                          float2* __restrict__ S) {
    int t = blockIdx.x;
    int c = threadIdx.x;               // 0..191
    float sr = 0.0f, si = 0.0f;
    #pragma unroll
    for (int plane = 0; plane < 3; ++plane) {
        int f = plane * 192 + c;
        int fi, sg; f_to_fi_sigma(f, fi, sg);
        float2 g0 = G[t * NF + f];
        float2 g1 = G[(t + FULLBLK) * NF + f];
        float2 qp = Qpart[(t + FULLBLK) * NF + f];
        float ur = g1.x - g0.x + qp.x;
        float ui = g1.y - g0.y + qp.y;
        unsigned ph = ((unsigned)fi * 128u * (unsigned)t) & 65535u;
        float frf = (float)ph * (1.0f / 65536.0f)
                  - (float)sg * (float)((128 * t) % MIN_WIN) * (1.0f / (float)MIN_WIN);
        frf -= rintf(frf);
        float sn, cs;
        __sincosf(6.283185307179586f * frf, &sn, &cs);
        float vr = ur * cs - ui * sn;
        float vi = ur * sn + ui * cs;
        float w = (plane == 0) ? 0.5f : -0.25f;
        sr = fmaf(w, vr, sr);
        si = fmaf(w, vi, si);
    }
    S[t * F_COMP + c] = make_float2(sr, si);
}

// power -> linear interp at CQT freqs -> log -> DCT (20x96)
__global__ void k_cqt(const float* __restrict__ S, float* __restrict__ cq) {
    __shared__ float lg[N_BINS];
    int t = blockIdx.x;
    int tid = threadIdx.x;
    if (tid < N_BINS) {
        float4 v = *(const float4*)(S + (size_t)t * 384 + tid * 4);
        float pl = v.x * v.x + v.y * v.y;
        float ph = v.z * v.z + v.w * v.w;
        float e    = (float)tid / 24.0f;
        float fb   = 32.7f * exp2f(e);
        float idxf = fb / 8000.0f * 32768.0f;
        float alpha = idxf - (float)((int)idxf);
        float p = (1.0f - alpha) * pl + alpha * ph;
        lg[tid] = logf(fmaxf(p, 1e-8f));
    }
    __syncthreads();
    if (tid < N_CQCC) {
        float s = 0.0f;
        for (int b = 0; b < N_BINS; ++b) {
            float arg = (float)M_PI * (float)(tid * (2 * b + 1)) / 192.0f;
            s += cosf(arg) * lg[b];
        }
        cq[t * N_CQCC + tid] = s;
    }
}

__global__ void k_stats(const float* __restrict__ cq, float* __restrict__ mean,
                        float* __restrict__ inv) {
    int k = blockIdx.x;
    int tid = threadIdx.x;
    double s = 0.0, sq = 0.0;
    for (int t = tid; t < T_FRAMES; t += 256) {
        double v = (double)cq[t * N_CQCC + k];
        s += v; sq += v * v;
    }
    #pragma unroll
    for (int off = 32; off > 0; off >>= 1) {
        s  += __shfl_down(s, off);
        sq += __shfl_down(sq, off);
    }
    __shared__ double rs[4], rq[4];
    int w = tid >> 6;
    if ((tid & 63) == 0) { rs[w] = s; rq[w] = sq; }
    __syncthreads();
    if (tid == 0) {
        s  = rs[0] + rs[1] + rs[2] + rs[3];
        sq = rq[0] + rq[1] + rq[2] + rq[3];
        double m = s / (double)T_FRAMES;
        double var = (sq - s * m) / (double)(T_FRAMES - 1);
        double sd = sqrt(var > 0.0 ? var : 0.0);
        mean[k] = (float)m;
        inv[k]  = (float)(1.0 / (sd + 1e-8));
    }
}

__device__ __forceinline__ int clampT(int v) {
    return v < 0 ? 0 : (v > T_FRAMES - 1 ? T_FRAMES - 1 : v);
}

__global__ void k_final(const float* __restrict__ cq, const float* __restrict__ mean,
                        const float* __restrict__ inv, float* __restrict__ out) {
    int gid = blockIdx.x * blockDim.x + threadIdx.x;
    if (gid >= T_FRAMES * N_CQCC) return;
    int t = gid / N_CQCC;
    int k = gid - t * N_CQCC;
    float m = mean[k], iv = inv[k];
    float cv[9];
    #pragma unroll
    for (int j = 0; j < 9; ++j)
        cv[j] = (cq[clampT(t + j - 4) * N_CQCC + k] - m) * iv;
    float dv[5];
    #pragma unroll
    for (int o = -2; o <= 2; ++o) {
        int p = clampT(t + o);
        int h1 = clampT(p + 1) - t, l1 = clampT(p - 1) - t;
        int h2 = clampT(p + 2) - t, l2 = clampT(p - 2) - t;
        dv[o + 2] = ((cv[h1 + 4] - cv[l1 + 4]) + 2.0f * (cv[h2 + 4] - cv[l2 + 4])) * 0.1f;
    }
    out[t * 60 + k]      = cv[4];
    out[t * 60 + 20 + k] = dv[2];
    out[t * 60 + 40 + k] = (dv[3] - dv[1] + 2.0f * (dv[4] - dv[0])) * 0.1f;
}

extern "C" void kernel_launch(void* const* d_in, const int* in_sizes, int n_in,
                              void* d_out, int out_size, void* d_ws, size_t ws_size,
                              hipStream_t stream) {
    const float* wav = (const float*)d_in[0];
    float* out = (float*)d_out;
    char* ws = (char*)d_ws;
    float*   xs    = (float*)(ws + WS_XS);
    float2*  E     = (float2*)(ws + WS_E);
    float2*  QF    = (float2*)(ws + WS_QF);   // Qfull, becomes G after k_scan3
    float2*  QP    = (float2*)(ws + WS_QP);
    double2* bsum  = (double2*)(ws + WS_BS);
    double2* offs  = (double2*)(ws + WS_OF);
    float2*  S     = (float2*)(ws + WS_S);
    float*   cq    = (float*)(ws + WS_CQ);
    float*   mean  = (float*)(ws + WS_MEAN);
    float*   inv   = (float*)(ws + WS_INV);

    k_init_xs<<<(XS_ALLOC + 255) / 256, 256, 0, stream>>>(wav, xs);
    k_E<<<(128 * NF + 255) / 256, 256, 0, stream>>>(E);
    k_chunk<<<dim3((NBLK + BT - 1) / BT, NF / FT), 256, 0, stream>>>(xs, E, QF, QP);
    k_scan1<<<(NF * NB64 + 255) / 256, 256, 0, stream>>>(QF, bsum);
    k_scan2<<<(NF + 255) / 256, 256, 0, stream>>>(bsum, offs);
    k_scan3<<<(NF * NB64 + 255) / 256, 256, 0, stream>>>(QF, offs);
    k_combine<<<T_FRAMES, 192, 0, stream>>>(QF, QP, S);
    k_cqt<<<T_FRAMES, 128, 0, stream>>>((const float*)S, cq);
    k_stats<<<N_CQCC, 256, 0, stream>>>(cq, mean, inv);
    k_final<<<(T_FRAMES * N_CQCC + 255) / 256, 256, 0, stream>>>(cq, mean, inv, out);
}

// Round 3
// 131.438 us; speedup vs baseline: 5.2928x; 1.1498x over previous
//
#include <hip/hip_runtime.h>
#include <math.h>

// ---- problem constants ----
#define WAV_N     262144
#define HOP       128
#define MIN_WIN   16699
#define LEFT      24418            // (65536 - 16699)/2
#define T_FRAMES  2049
#define N_BINS    96
#define N_CQCC    20
#define F_COMP    192              // 96 bins x {lo,hi}
#define NF        576              // 192 comps x 3 Hann planes
#define NBLK      2179             // 128-sample chunks covering xs
#define NBP       2240             // padded b-dim for [f][b] arrays
#define PARTLEN   59               // 16699 - 130*128
#define FULLBLK   130
#define XS_VALID  278843           // 2048*128 + 16699
#define XS_ALLOC  286720           // 128*2240: covers last chunk-tile read

// ---- chunk-matmul tiling: 256 thr = 16 f-pairs x 16 b-groups(4 b) ----
#define BT 64
#define FT 32
#define ASTRIDE 68                 // A_lds row stride (16B-aligned, conflict-breaking)

// ---- workspace layout (bytes) ----
#define WS_XS   0                  // 1,146,880
#define WS_E    1146880            // 589,824
#define WS_QF   1736704            // 10,321,920  [f][b] float2 (becomes G)
#define WS_QP   12058624           // 10,321,920
#define WS_S3   22380544           // 9,441,792   [t][576] float2 (rotated V)
#define WS_CQ   31822336           // 163,920
#define WS_MEAN 31986256
#define WS_INV  31986336

// f = plane*192 + c; c = bin*2 + hi; replicate reference f32 arithmetic for floor()
__device__ __forceinline__ void f_to_fi_sigma(int f, int& fi, int& sigma) {
    int plane = f / 192;
    int c = f - plane * 192;
    int bin = c >> 1, hi = c & 1;
    float e    = (float)bin / 24.0f;
    float fb   = 32.7f * exp2f(e);
    float idxf = fb / 8000.0f * 32768.0f;
    fi = (int)idxf + hi;
    sigma = (plane == 0) ? 0 : (plane == 1 ? 1 : -1);
}

// fused: xs reflect-pad  +  E twiddle table
__global__ void k_prep(const float* __restrict__ wav, float* __restrict__ xs,
                       float2* __restrict__ E) {
    int gid = blockIdx.x * blockDim.x + threadIdx.x;
    if (gid < XS_ALLOC) {
        float v = 0.0f;
        if (gid < XS_VALID) {
            int j = gid - 8350;                    // gid + LEFT - 32768
            if (j < 0) j = -j;
            if (j >= WAV_N) j = 2 * WAV_N - 2 - j;
            v = wav[j];
        }
        xs[gid] = v;
    } else {
        int ii = gid - XS_ALLOC;                   // < 128*NF
        int j = ii / NF, f = ii - j * NF;
        int fi, sg; f_to_fi_sigma(f, fi, sg);
        float fr = (float)((j * fi) & 65535) * (1.0f / 65536.0f)
                 - (float)sg * (float)j * (1.0f / (float)MIN_WIN);
        fr -= rintf(fr);
        float sn, cs;
        __sincosf(6.283185307179586f * fr, &sn, &cs);
        E[ii] = make_float2(cs, -sn);
    }
}

// Qfull[f][b] = e^{-i w0(b,f)} * sum_{j<128} xs[128b+j]*E[j][f]; Qpart = j<59 version
__global__ __launch_bounds__(256) void k_chunk(const float* __restrict__ xs,
                                               const float2* __restrict__ E,
                                               float2* __restrict__ Qfull,
                                               float2* __restrict__ Qpart) {
    __shared__ float A_lds[128 * ASTRIDE];         // [j][bl], bl<64
    __shared__ __align__(16) float4 E_lds[128 * 16]; // [j][ftp] = 2 f's (re0,im0,re1,im1)
    int tid = threadIdx.x;
    int b0 = blockIdx.x * BT;
    int f0 = blockIdx.y * FT;
    {
        const float* src = xs + 128 * b0;          // max 128*2176+8191 < XS_ALLOC
        #pragma unroll
        for (int i = 0; i < 32; ++i) {
            int m = i * 256 + tid;                 // m = 128*bl + j
            A_lds[(m & 127) * ASTRIDE + (m >> 7)] = src[m];
        }
    }
    {
        const float4* Eg = (const float4*)(E + f0);
        #pragma unroll
        for (int i = 0; i < 8; ++i) {
            int ii = i * 256 + tid;                // j*16 + ftp
            int j = ii >> 4, ftp = ii & 15;
            E_lds[ii] = Eg[j * (NF / 2) + ftp];
        }
    }
    __syncthreads();

    int ftp = tid & 15;            // f-pair: covers f0+2*ftp, f0+2*ftp+1
    int bg  = tid >> 4;            // 16 groups x 4 b
    float xr0[4] = {0,0,0,0}, xi0[4] = {0,0,0,0};
    float xr1[4] = {0,0,0,0}, xi1[4] = {0,0,0,0};
    float pr0[4], pi0[4], pr1[4], pi1[4];

    #pragma unroll 4
    for (int j = 0; j < PARTLEN; ++j) {
        float4 ev = E_lds[j * 16 + ftp];
        float4 a  = *(const float4*)&A_lds[j * ASTRIDE + bg * 4];
        const float aa[4] = {a.x, a.y, a.z, a.w};
        #pragma unroll
        for (int i = 0; i < 4; ++i) {
            xr0[i] = fmaf(aa[i], ev.x, xr0[i]); xi0[i] = fmaf(aa[i], ev.y, xi0[i]);
            xr1[i] = fmaf(aa[i], ev.z, xr1[i]); xi1[i] = fmaf(aa[i], ev.w, xi1[i]);
        }
    }
    #pragma unroll
    for (int i = 0; i < 4; ++i) {
        pr0[i] = xr0[i]; pi0[i] = xi0[i]; pr1[i] = xr1[i]; pi1[i] = xi1[i];
    }
    #pragma unroll 4
    for (int j = PARTLEN; j < 128; ++j) {
        float4 ev = E_lds[j * 16 + ftp];
        float4 a  = *(const float4*)&A_lds[j * ASTRIDE + bg * 4];
        const float aa[4] = {a.x, a.y, a.z, a.w};
        #pragma unroll
        for (int i = 0; i < 4; ++i) {
            xr0[i] = fmaf(aa[i], ev.x, xr0[i]); xi0[i] = fmaf(aa[i], ev.y, xi0[i]);
            xr1[i] = fmaf(aa[i], ev.z, xr1[i]); xi1[i] = fmaf(aa[i], ev.w, xi1[i]);
        }
    }

    int bBase = b0 + bg * 4;
    #pragma unroll
    for (int half = 0; half < 2; ++half) {
        int f = f0 + 2 * ftp + half;
        int fi, sg; f_to_fi_sigma(f, fi, sg);
        float2 qf[4], qp[4];
        #pragma unroll
        for (int i = 0; i < 4; ++i) {
            int b = bBase + i;
            unsigned ph = ((unsigned)fi * (unsigned)(LEFT + 128 * b)) & 65535u;
            float frf = (float)ph * (1.0f / 65536.0f)
                      - (float)sg * (float)((128 * b) % MIN_WIN) * (1.0f / (float)MIN_WIN);
            frf -= rintf(frf);
            float sn, cs;
            __sincosf(6.283185307179586f * frf, &sn, &cs);
            float fr_ = half ? xr1[i] : xr0[i], fi_ = half ? xi1[i] : xi0[i];
            float gr_ = half ? pr1[i] : pr0[i], gi_ = half ? pi1[i] : pi0[i];
            qf[i] = make_float2(fr_ * cs + fi_ * sn, fi_ * cs - fr_ * sn);
            qp[i] = make_float2(gr_ * cs + gi_ * sn, gi_ * cs - gr_ * sn);
        }
        float4* df = (float4*)&Qfull[(size_t)f * NBP + bBase];
        float4* dp = (float4*)&Qpart[(size_t)f * NBP + bBase];
        df[0] = make_float4(qf[0].x, qf[0].y, qf[1].x, qf[1].y);
        df[1] = make_float4(qf[2].x, qf[2].y, qf[3].x, qf[3].y);
        dp[0] = make_float4(qp[0].x, qp[0].y, qp[1].x, qp[1].y);
        dp[1] = make_float4(qp[2].x, qp[2].y, qp[3].x, qp[3].y);
    }
}

// one block per f: scan Qfull column (fp64), U = G[t+130]-G[t]+Qpart[t+130],
// rotate by e^{+i tau}, write V into [t][f] layout
#define SEG 9                      // 256*9 = 2304 >= 2179
__global__ __launch_bounds__(256) void k_scan(float2* __restrict__ Qf,
                                              const float2* __restrict__ Qp,
                                              float2* __restrict__ S3) {
    __shared__ float2 q[NBLK];
    __shared__ double2 tsum[256];
    int tid = threadIdx.x;
    int f = blockIdx.x;
    const float2* col = Qf + (size_t)f * NBP;
    #pragma unroll
    for (int k = 0; k < SEG; ++k) {
        int idx = k * 256 + tid;
        if (idx < NBLK) q[idx] = col[idx];
    }
    __syncthreads();
    // per-thread contiguous segment sum
    int s0 = tid * SEG;
    int s1 = min(s0 + SEG, NBLK);
    double sr = 0.0, si = 0.0;
    for (int i = s0; i < s1; ++i) { sr += q[i].x; si += q[i].y; }
    tsum[tid] = make_double2(sr, si);
    __syncthreads();
    // Hillis-Steele inclusive scan over 256 thread sums
    for (int s = 1; s < 256; s <<= 1) {
        double vr = 0.0, vi = 0.0;
        if (tid >= s) { vr = tsum[tid - s].x; vi = tsum[tid - s].y; }
        __syncthreads();
        if (tid >= s) { tsum[tid].x += vr; tsum[tid].y += vi; }
        __syncthreads();
    }
    double gr = (tid > 0) ? tsum[tid - 1].x : 0.0;
    double gi = (tid > 0) ? tsum[tid - 1].y : 0.0;
    // write exclusive prefix G back into q
    for (int i = s0; i < s1; ++i) {
        float2 old = q[i];
        q[i] = make_float2((float)gr, (float)gi);
        gr += old.x; gi += old.y;
    }
    __syncthreads();
    // U + rotate + scatter into [t][f]
    int fi, sg; f_to_fi_sigma(f, fi, sg);
    #pragma unroll
    for (int k = 0; k < SEG; ++k) {
        int t = k * 256 + tid;
        if (t >= T_FRAMES) break;
        float2 g0 = q[t];
        float2 g1 = q[t + FULLBLK];
        float2 qp = Qp[(size_t)f * NBP + t + FULLBLK];
        float ur = g1.x - g0.x + qp.x;
        float ui = g1.y - g0.y + qp.y;
        unsigned ph = ((unsigned)fi * 128u * (unsigned)t) & 65535u;
        float frf = (float)ph * (1.0f / 65536.0f)
                  - (float)sg * (float)((128 * t) % MIN_WIN) * (1.0f / (float)MIN_WIN);
        frf -= rintf(frf);
        float sn, cs;
        __sincosf(6.283185307179586f * frf, &sn, &cs);
        S3[(size_t)t * NF + f] = make_float2(ur * cs - ui * sn, ur * sn + ui * cs);
    }
}

// fold 3 Hann planes -> power -> interp -> log -> DCT
__global__ void k_cqt(const float2* __restrict__ S3, float* __restrict__ cq) {
    __shared__ float2 sc[F_COMP];
    __shared__ float lg[N_BINS];
    int t = blockIdx.x;
    int tid = threadIdx.x;                 // 192 threads
    if (tid < F_COMP) {
        const float2* row = S3 + (size_t)t * NF;
        float2 v0 = row[tid], v1 = row[192 + tid], v2 = row[384 + tid];
        sc[tid] = make_float2(0.5f * v0.x - 0.25f * (v1.x + v2.x),
                              0.5f * v0.y - 0.25f * (v1.y + v2.y));
    }
    __syncthreads();
    if (tid < N_BINS) {
        float2 lo = sc[tid * 2], hi = sc[tid * 2 + 1];
        float pl = lo.x * lo.x + lo.y * lo.y;
        float ph = hi.x * hi.x + hi.y * hi.y;
        float e    = (float)tid / 24.0f;
        float fb   = 32.7f * exp2f(e);
        float idxf = fb / 8000.0f * 32768.0f;
        float alpha = idxf - (float)((int)idxf);
        float p = (1.0f - alpha) * pl + alpha * ph;
        lg[tid] = logf(fmaxf(p, 1e-8f));
    }
    __syncthreads();
    if (tid < N_CQCC) {
        float s = 0.0f;
        for (int b = 0; b < N_BINS; ++b) {
            float arg = (float)M_PI * (float)(tid * (2 * b + 1)) / 192.0f;
            s += cosf(arg) * lg[b];
        }
        cq[t * N_CQCC + tid] = s;
    }
}

__global__ void k_stats(const float* __restrict__ cq, float* __restrict__ mean,
                        float* __restrict__ inv) {
    int k = blockIdx.x;
    int tid = threadIdx.x;
    double s = 0.0, sq = 0.0;
    for (int t = tid; t < T_FRAMES; t += 256) {
        double v = (double)cq[t * N_CQCC + k];
        s += v; sq += v * v;
    }
    #pragma unroll
    for (int off = 32; off > 0; off >>= 1) {
        s  += __shfl_down(s, off);
        sq += __shfl_down(sq, off);
    }
    __shared__ double rs[4], rq[4];
    int w = tid >> 6;
    if ((tid & 63) == 0) { rs[w] = s; rq[w] = sq; }
    __syncthreads();
    if (tid == 0) {
        s  = rs[0] + rs[1] + rs[2] + rs[3];
        sq = rq[0] + rq[1] + rq[2] + rq[3];
        double m = s / (double)T_FRAMES;
        double var = (sq - s * m) / (double)(T_FRAMES - 1);
        double sd = sqrt(var > 0.0 ? var : 0.0);
        mean[k] = (float)m;
        inv[k]  = (float)(1.0 / (sd + 1e-8));
    }
}

__device__ __forceinline__ int clampT(int v) {
    return v < 0 ? 0 : (v > T_FRAMES - 1 ? T_FRAMES - 1 : v);
}

__global__ void k_final(const float* __restrict__ cq, const float* __restrict__ mean,
                        const float* __restrict__ inv, float* __restrict__ out) {
    int gid = blockIdx.x * blockDim.x + threadIdx.x;
    if (gid >= T_FRAMES * N_CQCC) return;
    int t = gid / N_CQCC;
    int k = gid - t * N_CQCC;
    float m = mean[k], iv = inv[k];
    float cv[9];
    #pragma unroll
    for (int j = 0; j < 9; ++j)
        cv[j] = (cq[clampT(t + j - 4) * N_CQCC + k] - m) * iv;
    float dv[5];
    #pragma unroll
    for (int o = -2; o <= 2; ++o) {
        int p = clampT(t + o);
        int h1 = clampT(p + 1) - t, l1 = clampT(p - 1) - t;
        int h2 = clampT(p + 2) - t, l2 = clampT(p - 2) - t;
        dv[o + 2] = ((cv[h1 + 4] - cv[l1 + 4]) + 2.0f * (cv[h2 + 4] - cv[l2 + 4])) * 0.1f;
    }
    out[t * 60 + k]      = cv[4];
    out[t * 60 + 20 + k] = dv[2];
    out[t * 60 + 40 + k] = (dv[3] - dv[1] + 2.0f * (dv[4] - dv[0])) * 0.1f;
}

extern "C" void kernel_launch(void* const* d_in, const int* in_sizes, int n_in,
                              void* d_out, int out_size, void* d_ws, size_t ws_size,
                              hipStream_t stream) {
    const float* wav = (const float*)d_in[0];
    float* out = (float*)d_out;
    char* ws = (char*)d_ws;
    float*  xs   = (float*)(ws + WS_XS);
    float2* E    = (float2*)(ws + WS_E);
    float2* QF   = (float2*)(ws + WS_QF);
    float2* QP   = (float2*)(ws + WS_QP);
    float2* S3   = (float2*)(ws + WS_S3);
    float*  cq   = (float*)(ws + WS_CQ);
    float*  mean = (float*)(ws + WS_MEAN);
    float*  inv  = (float*)(ws + WS_INV);

    k_prep<<<(XS_ALLOC + 128 * NF) / 256, 256, 0, stream>>>(wav, xs, E);
    k_chunk<<<dim3((NBLK + BT - 1) / BT, NF / FT), 256, 0, stream>>>(xs, E, QF, QP);
    k_scan<<<NF, 256, 0, stream>>>(QF, QP, S3);
    k_cqt<<<T_FRAMES, 192, 0, stream>>>(S3, cq);
    k_stats<<<N_CQCC, 256, 0, stream>>>(cq, mean, inv);
    k_final<<<(T_FRAMES * N_CQCC + 255) / 256, 256, 0, stream>>>(cq, mean, inv, out);
}

// Round 4
// 124.980 us; speedup vs baseline: 5.5663x; 1.0517x over previous
//
#include <hip/hip_runtime.h>
#include <math.h>

// ---- problem constants ----
#define WAV_N     262144
#define HOP       128
#define MIN_WIN   16699
#define LEFT      24418            // (65536 - 16699)/2
#define T_FRAMES  2049
#define N_BINS    96
#define N_CQCC    20
#define F_COMP    192              // 96 bins x {lo,hi}
#define NF        576              // 192 comps x 3 Hann planes
#define NBLK      2179             // 128-sample chunks covering padded signal
#define NBP       2240             // padded b-dim for QFP rows
#define PARTLEN   59               // 16699 - 130*128
#define FULLBLK   130
#define XS_VALID  278843           // 2048*128 + 16699

// ---- chunk-matmul tiling: 256 thr = 16 f-pairs x 16 b-groups(4 b) ----
#define BT 64
#define FT 32
#define ASTRIDE 68

// ---- workspace layout (bytes) ----
#define WS_QFP  0                  // 576*2240*16 = 20,643,840  float4(qf.re,qf.im,qp.re,qp.im)
#define WS_SC   20643840           // 192*2056*8  =  3,158,016  folded spectrum [c][t]
#define WS_CQ   23801856           // 2049*20*4   =    163,920
#define WS_SUMS 23965776           // 40 doubles
#define SCP     2056               // Sc row stride (float2 units)

// f = plane*192 + c; c = bin*2 + hi; replicate reference f32 arithmetic for floor()
__device__ __forceinline__ void f_to_fi_sigma(int f, int& fi, int& sigma) {
    int plane = f / 192;
    int c = f - plane * 192;
    int bin = c >> 1, hi = c & 1;
    float e    = (float)bin / 24.0f;
    float fb   = 32.7f * exp2f(e);
    float idxf = fb / 8000.0f * 32768.0f;
    fi = (int)idxf + hi;
    sigma = (plane == 0) ? 0 : (plane == 1 ? 1 : -1);
}

// QFP[f][b] = (qf, qp): qf = e^{-i w0} sum_{j<128} xs[128b+j] E[j][f], qp = j<59 version
__global__ __launch_bounds__(256) void k_chunk(const float* __restrict__ wav,
                                               float4* __restrict__ QFP) {
    __shared__ float A_lds[128 * ASTRIDE];             // [j][bl], bl<64
    __shared__ __align__(16) float4 E_lds[128 * 16];   // [j][ftp]: 2 f's packed
    int tid = threadIdx.x;
    int b0 = blockIdx.x * BT;
    int f0 = blockIdx.y * FT;

    // A-tile: reflect-pad straight from wav
    {
        int sbase = 128 * b0;
        #pragma unroll
        for (int i = 0; i < 32; ++i) {
            int m = i * 256 + tid;                     // m = 128*bl + j
            int s = sbase + m;
            float v = 0.0f;
            if (s < XS_VALID) {
                int j = s - 8350;                      // s + LEFT - 32768
                if (j < 0) j = -j;
                if (j >= WAV_N) j = 2 * WAV_N - 2 - j;
                v = wav[j];
            }
            A_lds[(m & 127) * ASTRIDE + (m >> 7)] = v;
        }
    }
    // E-tile computed in-block
    {
        #pragma unroll
        for (int i = 0; i < 8; ++i) {
            int ii = i * 256 + tid;                    // j*16 + ftp
            int j = ii >> 4, ftp = ii & 15;
            float4 ev;
            #pragma unroll
            for (int half = 0; half < 2; ++half) {
                int f = f0 + 2 * ftp + half;
                int fi, sg; f_to_fi_sigma(f, fi, sg);
                float fr = (float)((j * fi) & 65535) * (1.0f / 65536.0f)
                         - (float)sg * (float)j * (1.0f / (float)MIN_WIN);
                fr -= rintf(fr);
                float sn, cs;
                __sincosf(6.283185307179586f * fr, &sn, &cs);
                if (half == 0) { ev.x = cs; ev.y = -sn; }
                else           { ev.z = cs; ev.w = -sn; }
            }
            E_lds[ii] = ev;
        }
    }
    __syncthreads();

    int ftp = tid & 15;
    int bg  = tid >> 4;
    float xr0[4] = {0,0,0,0}, xi0[4] = {0,0,0,0};
    float xr1[4] = {0,0,0,0}, xi1[4] = {0,0,0,0};
    float pr0[4], pi0[4], pr1[4], pi1[4];

    #pragma unroll 4
    for (int j = 0; j < PARTLEN; ++j) {
        float4 ev = E_lds[j * 16 + ftp];
        float4 a  = *(const float4*)&A_lds[j * ASTRIDE + bg * 4];
        const float aa[4] = {a.x, a.y, a.z, a.w};
        #pragma unroll
        for (int i = 0; i < 4; ++i) {
            xr0[i] = fmaf(aa[i], ev.x, xr0[i]); xi0[i] = fmaf(aa[i], ev.y, xi0[i]);
            xr1[i] = fmaf(aa[i], ev.z, xr1[i]); xi1[i] = fmaf(aa[i], ev.w, xi1[i]);
        }
    }
    #pragma unroll
    for (int i = 0; i < 4; ++i) {
        pr0[i] = xr0[i]; pi0[i] = xi0[i]; pr1[i] = xr1[i]; pi1[i] = xi1[i];
    }
    #pragma unroll 4
    for (int j = PARTLEN; j < 128; ++j) {
        float4 ev = E_lds[j * 16 + ftp];
        float4 a  = *(const float4*)&A_lds[j * ASTRIDE + bg * 4];
        const float aa[4] = {a.x, a.y, a.z, a.w};
        #pragma unroll
        for (int i = 0; i < 4; ++i) {
            xr0[i] = fmaf(aa[i], ev.x, xr0[i]); xi0[i] = fmaf(aa[i], ev.y, xi0[i]);
            xr1[i] = fmaf(aa[i], ev.z, xr1[i]); xi1[i] = fmaf(aa[i], ev.w, xi1[i]);
        }
    }

    int bBase = b0 + bg * 4;
    #pragma unroll
    for (int half = 0; half < 2; ++half) {
        int f = f0 + 2 * ftp + half;
        int fi, sg; f_to_fi_sigma(f, fi, sg);
        float4* dst = QFP + (size_t)f * NBP + bBase;
        #pragma unroll
        for (int i = 0; i < 4; ++i) {
            int b = bBase + i;
            unsigned ph = ((unsigned)fi * (unsigned)(LEFT + 128 * b)) & 65535u;
            float frf = (float)ph * (1.0f / 65536.0f)
                      - (float)sg * (float)((128 * b) % MIN_WIN) * (1.0f / (float)MIN_WIN);
            frf -= rintf(frf);
            float sn, cs;
            __sincosf(6.283185307179586f * frf, &sn, &cs);
            float fr_ = half ? xr1[i] : xr0[i], fi_ = half ? xi1[i] : xi0[i];
            float gr_ = half ? pr1[i] : pr0[i], gi_ = half ? pi1[i] : pi0[i];
            dst[i] = make_float4(fr_ * cs + fi_ * sn, fi_ * cs - fr_ * sn,
                                 gr_ * cs + gi_ * sn, gi_ * cs - gr_ * sn);
        }
    }
}

// one block per component c: scan 3 plane-columns (fp64), U = G[t+130]-G[t]+qp[t+130],
// rotate by e^{+i tau}, fold planes (0.5, -0.25, -0.25), write Sc[c][t]
#define SEG 9                      // 256*9 >= 2179
__global__ __launch_bounds__(256) void k_scan(const float4* __restrict__ QFP,
                                              float2* __restrict__ Sc,
                                              double* __restrict__ sums) {
    __shared__ float4 col[NBLK];       // 34,864 B
    __shared__ float2 acc[T_FRAMES];   // 16,392 B
    __shared__ double2 wsum[4];
    int tid = threadIdx.x;
    int c = blockIdx.x;
    if (c == 0 && tid < 40) sums[tid] = 0.0;   // zero stats accumulators

    for (int plane = 0; plane < 3; ++plane) {
        int f = plane * 192 + c;
        const float4* g = QFP + (size_t)f * NBP;
        #pragma unroll
        for (int k = 0; k < SEG; ++k) {
            int idx = k * 256 + tid;
            if (idx < NBLK) col[idx] = g[idx];
        }
        __syncthreads();
        // per-thread segment sum (fp64)
        int s0 = tid * SEG, s1 = min(s0 + SEG, NBLK);
        double sr = 0.0, si = 0.0;
        for (int i = s0; i < s1; ++i) { sr += col[i].x; si += col[i].y; }
        // wave inclusive scan
        double r = sr, im = si;
        #pragma unroll
        for (int off = 1; off < 64; off <<= 1) {
            double pr = __shfl_up(r, off);
            double pi = __shfl_up(im, off);
            if ((tid & 63) >= off) { r += pr; im += pi; }
        }
        if ((tid & 63) == 63) wsum[tid >> 6] = make_double2(r, im);
        __syncthreads();
        double basr = 0.0, basi = 0.0;
        int w = tid >> 6;
        for (int ww = 0; ww < w; ++ww) { basr += wsum[ww].x; basi += wsum[ww].y; }
        double gr = basr + r - sr, gi = basi + im - si;   // exclusive prefix at s0
        // overwrite col[].xy with exclusive prefix G
        for (int i = s0; i < s1; ++i) {
            float qx = col[i].x, qy = col[i].y;
            col[i].x = (float)gr; col[i].y = (float)gi;
            gr += qx; gi += qy;
        }
        __syncthreads();
        // U + rotate + fold
        int fi_, sg_; f_to_fi_sigma(f, fi_, sg_);
        #pragma unroll
        for (int k = 0; k < SEG; ++k) {
            int t = k * 256 + tid;
            if (t < T_FRAMES) {
                float4 ca = col[t];
                float4 cb = col[t + FULLBLK];
                float ur = cb.x - ca.x + cb.z;
                float ui = cb.y - ca.y + cb.w;
                unsigned ph = ((unsigned)fi_ * 128u * (unsigned)t) & 65535u;
                float frf = (float)ph * (1.0f / 65536.0f)
                          - (float)sg_ * (float)((128 * t) % MIN_WIN) * (1.0f / (float)MIN_WIN);
                frf -= rintf(frf);
                float sn, cs;
                __sincosf(6.283185307179586f * frf, &sn, &cs);
                float vr = ur * cs - ui * sn;
                float vi = ur * sn + ui * cs;
                if (plane == 0) acc[t] = make_float2(0.5f * vr, 0.5f * vi);
                else { acc[t].x -= 0.25f * vr; acc[t].y -= 0.25f * vi; }
            }
        }
        __syncthreads();
    }
    #pragma unroll
    for (int k = 0; k < SEG; ++k) {
        int t = k * 256 + tid;
        if (t < T_FRAMES) Sc[(size_t)c * SCP + t] = acc[t];
    }
}

// 8 frames/block: power -> interp -> log -> DCT; fp64 atomic stats partials
__global__ __launch_bounds__(256) void k_cqt(const float2* __restrict__ Sc,
                                             float* __restrict__ cq,
                                             double* __restrict__ sums) {
    __shared__ float dctm[N_CQCC * N_BINS];  // 7680 B
    __shared__ float lg[8][N_BINS];
    __shared__ float cqv[8][N_CQCC];
    int tid = threadIdx.x;
    int tb = blockIdx.x * 8;
    for (int idx = tid; idx < N_CQCC * N_BINS; idx += 256) {
        int k = idx / N_BINS, b = idx - k * N_BINS;
        dctm[idx] = cosf((float)M_PI * (float)(k * (2 * b + 1)) / 192.0f);
    }
    int lt = tid >> 5, lane = tid & 31;
    int t = tb + lt;
    #pragma unroll
    for (int bb = 0; bb < 3; ++bb) {
        int b = lane + 32 * bb;
        float lv = 0.0f;
        if (t < T_FRAMES) {
            float2 lo = Sc[(size_t)(2 * b) * SCP + t];
            float2 hi = Sc[(size_t)(2 * b + 1) * SCP + t];
            float pl = lo.x * lo.x + lo.y * lo.y;
            float ph = hi.x * hi.x + hi.y * hi.y;
            float e    = (float)b / 24.0f;
            float fb   = 32.7f * exp2f(e);
            float idxf = fb / 8000.0f * 32768.0f;
            float alpha = idxf - (float)((int)idxf);
            float p = (1.0f - alpha) * pl + alpha * ph;
            lv = logf(fmaxf(p, 1e-8f));
        }
        lg[lt][b] = lv;
    }
    __syncthreads();
    if (tid < 8 * N_CQCC) {
        int lt2 = tid / N_CQCC, k = tid - lt2 * N_CQCC;
        int t2 = tb + lt2;
        float s = 0.0f;
        #pragma unroll 4
        for (int b = 0; b < N_BINS; ++b) s += dctm[k * N_BINS + b] * lg[lt2][b];
        cqv[lt2][k] = (t2 < T_FRAMES) ? s : 0.0f;
        if (t2 < T_FRAMES) cq[t2 * N_CQCC + k] = s;
    }
    __syncthreads();
    if (tid < N_CQCC) {
        double s1 = 0.0, s2 = 0.0;
        #pragma unroll
        for (int lt2 = 0; lt2 < 8; ++lt2) {
            if (tb + lt2 < T_FRAMES) {
                double v = (double)cqv[lt2][tid];
                s1 += v; s2 += v * v;
            }
        }
        atomicAdd(&sums[tid], s1);
        atomicAdd(&sums[N_CQCC + tid], s2);
    }
}

__device__ __forceinline__ int clampT(int v) {
    return v < 0 ? 0 : (v > T_FRAMES - 1 ? T_FRAMES - 1 : v);
}

// normalize + delta + delta-delta; mean/inv derived inline from fp64 sums
__global__ void k_final(const float* __restrict__ cq, const double* __restrict__ sums,
                        float* __restrict__ out) {
    int gid = blockIdx.x * blockDim.x + threadIdx.x;
    if (gid >= T_FRAMES * N_CQCC) return;
    int t = gid / N_CQCC;
    int k = gid - t * N_CQCC;
    double S1 = sums[k], S2 = sums[N_CQCC + k];
    double md = S1 / (double)T_FRAMES;
    double var = (S2 - S1 * md) / (double)(T_FRAMES - 1);
    double sd = sqrt(var > 0.0 ? var : 0.0);
    float m = (float)md;
    float iv = (float)(1.0 / (sd + 1e-8));
    float cv[9];
    #pragma unroll
    for (int j = 0; j < 9; ++j)
        cv[j] = (cq[clampT(t + j - 4) * N_CQCC + k] - m) * iv;
    float dv[5];
    #pragma unroll
    for (int o = -2; o <= 2; ++o) {
        int p = clampT(t + o);
        int h1 = clampT(p + 1) - t, l1 = clampT(p - 1) - t;
        int h2 = clampT(p + 2) - t, l2 = clampT(p - 2) - t;
        dv[o + 2] = ((cv[h1 + 4] - cv[l1 + 4]) + 2.0f * (cv[h2 + 4] - cv[l2 + 4])) * 0.1f;
    }
    out[t * 60 + k]      = cv[4];
    out[t * 60 + 20 + k] = dv[2];
    out[t * 60 + 40 + k] = (dv[3] - dv[1] + 2.0f * (dv[4] - dv[0])) * 0.1f;
}

extern "C" void kernel_launch(void* const* d_in, const int* in_sizes, int n_in,
                              void* d_out, int out_size, void* d_ws, size_t ws_size,
                              hipStream_t stream) {
    const float* wav = (const float*)d_in[0];
    float* out = (float*)d_out;
    char* ws = (char*)d_ws;
    float4* QFP  = (float4*)(ws + WS_QFP);
    float2* Sc   = (float2*)(ws + WS_SC);
    float*  cq   = (float*)(ws + WS_CQ);
    double* sums = (double*)(ws + WS_SUMS);

    k_chunk<<<dim3((NBLK + BT - 1) / BT, NF / FT), 256, 0, stream>>>(wav, QFP);
    k_scan<<<F_COMP, 256, 0, stream>>>(QFP, Sc, sums);
    k_cqt<<<(T_FRAMES + 7) / 8, 256, 0, stream>>>(Sc, cq, sums);
    k_final<<<(T_FRAMES * N_CQCC + 255) / 256, 256, 0, stream>>>(cq, sums, out);
}

// Round 5
// 120.798 us; speedup vs baseline: 5.7590x; 1.0346x over previous
//
#include <hip/hip_runtime.h>
#include <math.h>

// ---- problem constants ----
#define WAV_N     262144
#define HOP       128
#define MIN_WIN   16699
#define LEFT      24418            // (65536 - 16699)/2
#define T_FRAMES  2049
#define N_BINS    96
#define N_CQCC    20
#define F_COMP    192              // 96 bins x {lo,hi}
#define NF        576              // 192 comps x 3 Hann planes
#define NBLK      2179             // 128-sample chunks covering padded signal
#define NBP       2240             // padded b-dim for QFP rows (= 35*64)
#define PARTLEN   59               // 16699 - 130*128
#define FULLBLK   130
#define XS_VALID  278843           // 2048*128 + 16699
#define TWOPI     6.283185307179586f

// ---- chunk kernel tiling: 256 thr = 32 f-pairs x 8 b-groups(8 b each) ----
#define BT   64
#define FTW  64
#define JC   32
#define AST  68                    // A_lds row stride (272 B, 16B-aligned)

// ---- workspace layout (bytes) ----
#define WS_QFP  0                  // 576*2240*16 = 20,643,840  float4(qf.re,qf.im,qp.re,qp.im)
#define WS_SC   20643840           // 192*2056*8  =  3,158,016  folded spectrum [c][t]
#define WS_CQ   23801856           // 2049*20*4   =    163,920
#define WS_SUMS 23965776           // 40 doubles
#define SCP     2056               // Sc row stride (float2 units)

// f = plane*192 + c; c = bin*2 + hi; replicate reference f32 arithmetic for floor()
__device__ __forceinline__ void f_to_fi_sigma(int f, int& fi, int& sigma) {
    int plane = f / 192;
    int c = f - plane * 192;
    int bin = c >> 1, hi = c & 1;
    float e    = (float)bin / 24.0f;
    float fb   = 32.7f * exp2f(e);
    float idxf = fb / 8000.0f * 32768.0f;
    fi = (int)idxf + hi;
    sigma = (plane == 0) ? 0 : (plane == 1 ? 1 : -1);
}

// QFP[f][b] = (qf, qp): qf = e^{-i w0} sum_{j<128} xs[128b+j] E[j][f], qp = j<59 version
// E via register rotators re-anchored every 32 j; A staged in 32-j LDS chunks.
__global__ __launch_bounds__(256) void k_chunk(const float* __restrict__ wav,
                                               float4* __restrict__ QFP) {
    __shared__ float A_lds[JC * AST];              // 8704 B
    int tid = threadIdx.x;
    int b0 = blockIdx.x * BT;
    int f0 = blockIdx.y * FTW;
    int ftp = tid & 31;                            // f-pair index
    int bg  = tid >> 5;                            // 8 groups x 8 b
    int bb  = b0 + bg * 8;

    int fi[2], sg[2];
    f_to_fi_sigma(f0 + 2 * ftp,     fi[0], sg[0]);
    f_to_fi_sigma(f0 + 2 * ftp + 1, fi[1], sg[1]);

    // per-j rotator step D[f] = e^{-2*pi*i*(fi/65536 - sg/W)}
    float Dr[2], Di[2];
    #pragma unroll
    for (int h = 0; h < 2; ++h) {
        float fr = (float)fi[h] * (1.0f / 65536.0f)
                 - (float)sg[h] * (1.0f / (float)MIN_WIN);
        fr -= rintf(fr);
        float sn, cs; __sincosf(TWOPI * fr, &sn, &cs);
        Dr[h] = cs; Di[h] = -sn;
    }

    float xr[2][8], xi[2][8], pr[2][8], pi[2][8];
    #pragma unroll
    for (int h = 0; h < 2; ++h)
        #pragma unroll
        for (int i = 0; i < 8; ++i) { xr[h][i] = 0.f; xi[h][i] = 0.f; }

    for (int jc = 0; jc < 4; ++jc) {
        int jbase = jc * JC;
        __syncthreads();
        // stage A chunk: A_lds[j][bl] = xs[128*(b0+bl) + jbase + j], reflect from wav
        #pragma unroll
        for (int i = 0; i < 8; ++i) {
            int m = i * 256 + tid;                 // 32j x 64bl
            int j = m & 31, bl = m >> 5;
            int s = 128 * (b0 + bl) + jbase + j;
            float v = 0.0f;
            if (s < XS_VALID) {
                int w = s - 8350;                  // s + LEFT - 32768
                if (w < 0) w = -w;
                if (w >= WAV_N) w = 2 * WAV_N - 2 - w;
                v = wav[w];
            }
            A_lds[j * AST + bl] = v;
        }
        __syncthreads();
        // anchor rotators at j = jbase (exact integer phase)
        float Wr[2], Wi[2];
        #pragma unroll
        for (int h = 0; h < 2; ++h) {
            float fr = (float)((jbase * fi[h]) & 65535) * (1.0f / 65536.0f)
                     - (float)sg[h] * (float)jbase * (1.0f / (float)MIN_WIN);
            fr -= rintf(fr);
            float sn, cs; __sincosf(TWOPI * fr, &sn, &cs);
            Wr[h] = cs; Wi[h] = -sn;
        }
        #pragma unroll 8
        for (int j32 = 0; j32 < JC; ++j32) {
            if (jc == 1 && j32 == PARTLEN - 32) {  // snapshot partial sum (j<59)
                #pragma unroll
                for (int h = 0; h < 2; ++h)
                    #pragma unroll
                    for (int i = 0; i < 8; ++i) { pr[h][i] = xr[h][i]; pi[h][i] = xi[h][i]; }
            }
            float4 a0 = *(const float4*)&A_lds[j32 * AST + bg * 8];
            float4 a1 = *(const float4*)&A_lds[j32 * AST + bg * 8 + 4];
            const float aa[8] = {a0.x, a0.y, a0.z, a0.w, a1.x, a1.y, a1.z, a1.w};
            #pragma unroll
            for (int h = 0; h < 2; ++h) {
                float wr = Wr[h], wi = Wi[h];
                #pragma unroll
                for (int i = 0; i < 8; ++i) {
                    xr[h][i] = fmaf(aa[i], wr, xr[h][i]);
                    xi[h][i] = fmaf(aa[i], wi, xi[h][i]);
                }
                Wr[h] = wr * Dr[h] - wi * Di[h];
                Wi[h] = wr * Di[h] + wi * Dr[h];
            }
        }
    }

    // apply e^{-i w0(b,f)} and store (qf, qp) interleaved; b>=NBLK lands in row pad
    #pragma unroll
    for (int h = 0; h < 2; ++h) {
        int f = f0 + 2 * ftp + h;
        float4* dst = QFP + (size_t)f * NBP + bb;
        #pragma unroll
        for (int i = 0; i < 8; ++i) {
            int b = bb + i;
            unsigned ph = ((unsigned)fi[h] * (unsigned)(LEFT + 128 * b)) & 65535u;
            float frf = (float)ph * (1.0f / 65536.0f)
                      - (float)sg[h] * (float)((128 * b) % MIN_WIN) * (1.0f / (float)MIN_WIN);
            frf -= rintf(frf);
            float sn, cs; __sincosf(TWOPI * frf, &sn, &cs);
            dst[i] = make_float4(xr[h][i] * cs + xi[h][i] * sn,
                                 xi[h][i] * cs - xr[h][i] * sn,
                                 pr[h][i] * cs + pi[h][i] * sn,
                                 pi[h][i] * cs - pr[h][i] * sn);
        }
    }
}

// one block per component c: scan 3 plane-columns (fp64), U = G[t+130]-G[t]+qp[t+130],
// rotate by e^{+i tau}, fold planes (0.5, -0.25, -0.25), write Sc[c][t]
#define SEG 9                      // 256*9 >= 2179
__global__ __launch_bounds__(256) void k_scan(const float4* __restrict__ QFP,
                                              float2* __restrict__ Sc,
                                              double* __restrict__ sums) {
    __shared__ float4 col[NBLK];       // 34,864 B
    __shared__ float2 acc[T_FRAMES];   // 16,392 B
    __shared__ double2 wsum[4];
    int tid = threadIdx.x;
    int c = blockIdx.x;
    if (c == 0 && tid < 40) sums[tid] = 0.0;   // zero stats accumulators

    for (int plane = 0; plane < 3; ++plane) {
        int f = plane * 192 + c;
        const float4* g = QFP + (size_t)f * NBP;
        #pragma unroll
        for (int k = 0; k < SEG; ++k) {
            int idx = k * 256 + tid;
            if (idx < NBLK) col[idx] = g[idx];
        }
        __syncthreads();
        int s0 = tid * SEG, s1 = min(s0 + SEG, NBLK);
        double sr = 0.0, si = 0.0;
        for (int i = s0; i < s1; ++i) { sr += col[i].x; si += col[i].y; }
        double r = sr, im = si;
        #pragma unroll
        for (int off = 1; off < 64; off <<= 1) {
            double prx = __shfl_up(r, off);
            double piy = __shfl_up(im, off);
            if ((tid & 63) >= off) { r += prx; im += piy; }
        }
        if ((tid & 63) == 63) wsum[tid >> 6] = make_double2(r, im);
        __syncthreads();
        double basr = 0.0, basi = 0.0;
        int w = tid >> 6;
        for (int ww = 0; ww < w; ++ww) { basr += wsum[ww].x; basi += wsum[ww].y; }
        double gr = basr + r - sr, gi = basi + im - si;   // exclusive prefix at s0
        for (int i = s0; i < s1; ++i) {
            float qx = col[i].x, qy = col[i].y;
            col[i].x = (float)gr; col[i].y = (float)gi;
            gr += qx; gi += qy;
        }
        __syncthreads();
        int fi_, sg_; f_to_fi_sigma(f, fi_, sg_);
        #pragma unroll
        for (int k = 0; k < SEG; ++k) {
            int t = k * 256 + tid;
            if (t < T_FRAMES) {
                float4 ca = col[t];
                float4 cb = col[t + FULLBLK];
                float ur = cb.x - ca.x + cb.z;
                float ui = cb.y - ca.y + cb.w;
                unsigned ph = ((unsigned)fi_ * 128u * (unsigned)t) & 65535u;
                float frf = (float)ph * (1.0f / 65536.0f)
                          - (float)sg_ * (float)((128 * t) % MIN_WIN) * (1.0f / (float)MIN_WIN);
                frf -= rintf(frf);
                float sn, cs;
                __sincosf(TWOPI * frf, &sn, &cs);
                float vr = ur * cs - ui * sn;
                float vi = ur * sn + ui * cs;
                if (plane == 0) acc[t] = make_float2(0.5f * vr, 0.5f * vi);
                else { acc[t].x -= 0.25f * vr; acc[t].y -= 0.25f * vi; }
            }
        }
        __syncthreads();
    }
    #pragma unroll
    for (int k = 0; k < SEG; ++k) {
        int t = k * 256 + tid;
        if (t < T_FRAMES) Sc[(size_t)c * SCP + t] = acc[t];
    }
}

// 8 frames/block: power -> interp -> log -> DCT; fp64 atomic stats partials
__global__ __launch_bounds__(256) void k_cqt(const float2* __restrict__ Sc,
                                             float* __restrict__ cq,
                                             double* __restrict__ sums) {
    __shared__ float dctm[N_CQCC * N_BINS];  // 7680 B
    __shared__ float lg[8][N_BINS];
    __shared__ float cqv[8][N_CQCC];
    int tid = threadIdx.x;
    int tb = blockIdx.x * 8;
    for (int idx = tid; idx < N_CQCC * N_BINS; idx += 256) {
        int k = idx / N_BINS, b = idx - k * N_BINS;
        dctm[idx] = cosf((float)M_PI * (float)(k * (2 * b + 1)) / 192.0f);
    }
    int lt = tid >> 5, lane = tid & 31;
    int t = tb + lt;
    #pragma unroll
    for (int bb = 0; bb < 3; ++bb) {
        int b = lane + 32 * bb;
        float lv = 0.0f;
        if (t < T_FRAMES) {
            float2 lo = Sc[(size_t)(2 * b) * SCP + t];
            float2 hi = Sc[(size_t)(2 * b + 1) * SCP + t];
            float pl = lo.x * lo.x + lo.y * lo.y;
            float ph = hi.x * hi.x + hi.y * hi.y;
            float e    = (float)b / 24.0f;
            float fb   = 32.7f * exp2f(e);
            float idxf = fb / 8000.0f * 32768.0f;
            float alpha = idxf - (float)((int)idxf);
            float p = (1.0f - alpha) * pl + alpha * ph;
            lv = logf(fmaxf(p, 1e-8f));
        }
        lg[lt][b] = lv;
    }
    __syncthreads();
    if (tid < 8 * N_CQCC) {
        int lt2 = tid / N_CQCC, k = tid - lt2 * N_CQCC;
        int t2 = tb + lt2;
        float s = 0.0f;
        #pragma unroll 4
        for (int b = 0; b < N_BINS; ++b) s += dctm[k * N_BINS + b] * lg[lt2][b];
        cqv[lt2][k] = (t2 < T_FRAMES) ? s : 0.0f;
        if (t2 < T_FRAMES) cq[t2 * N_CQCC + k] = s;
    }
    __syncthreads();
    if (tid < N_CQCC) {
        double s1 = 0.0, s2 = 0.0;
        #pragma unroll
        for (int lt2 = 0; lt2 < 8; ++lt2) {
            if (tb + lt2 < T_FRAMES) {
                double v = (double)cqv[lt2][tid];
                s1 += v; s2 += v * v;
            }
        }
        atomicAdd(&sums[tid], s1);
        atomicAdd(&sums[N_CQCC + tid], s2);
    }
}

__device__ __forceinline__ int clampT(int v) {
    return v < 0 ? 0 : (v > T_FRAMES - 1 ? T_FRAMES - 1 : v);
}

// normalize + delta + delta-delta; mean/inv derived inline from fp64 sums
__global__ void k_final(const float* __restrict__ cq, const double* __restrict__ sums,
                        float* __restrict__ out) {
    int gid = blockIdx.x * blockDim.x + threadIdx.x;
    if (gid >= T_FRAMES * N_CQCC) return;
    int t = gid / N_CQCC;
    int k = gid - t * N_CQCC;
    double S1 = sums[k], S2 = sums[N_CQCC + k];
    double md = S1 / (double)T_FRAMES;
    double var = (S2 - S1 * md) / (double)(T_FRAMES - 1);
    double sd = sqrt(var > 0.0 ? var : 0.0);
    float m = (float)md;
    float iv = (float)(1.0 / (sd + 1e-8));
    float cv[9];
    #pragma unroll
    for (int j = 0; j < 9; ++j)
        cv[j] = (cq[clampT(t + j - 4) * N_CQCC + k] - m) * iv;
    float dv[5];
    #pragma unroll
    for (int o = -2; o <= 2; ++o) {
        int p = clampT(t + o);
        int h1 = clampT(p + 1) - t, l1 = clampT(p - 1) - t;
        int h2 = clampT(p + 2) - t, l2 = clampT(p - 2) - t;
        dv[o + 2] = ((cv[h1 + 4] - cv[l1 + 4]) + 2.0f * (cv[h2 + 4] - cv[l2 + 4])) * 0.1f;
    }
    out[t * 60 + k]      = cv[4];
    out[t * 60 + 20 + k] = dv[2];
    out[t * 60 + 40 + k] = (dv[3] - dv[1] + 2.0f * (dv[4] - dv[0])) * 0.1f;
}

extern "C" void kernel_launch(void* const* d_in, const int* in_sizes, int n_in,
                              void* d_out, int out_size, void* d_ws, size_t ws_size,
                              hipStream_t stream) {
    const float* wav = (const float*)d_in[0];
    float* out = (float*)d_out;
    char* ws = (char*)d_ws;
    float4* QFP  = (float4*)(ws + WS_QFP);
    float2* Sc   = (float2*)(ws + WS_SC);
    float*  cq   = (float*)(ws + WS_CQ);
    double* sums = (double*)(ws + WS_SUMS);

    k_chunk<<<dim3(NBP / BT, NF / FTW), 256, 0, stream>>>(wav, QFP);
    k_scan<<<F_COMP, 256, 0, stream>>>(QFP, Sc, sums);
    k_cqt<<<(T_FRAMES + 7) / 8, 256, 0, stream>>>(Sc, cq, sums);
    k_final<<<(T_FRAMES * N_CQCC + 255) / 256, 256, 0, stream>>>(cq, sums, out);
}

// Round 6
// 117.454 us; speedup vs baseline: 5.9230x; 1.0285x over previous
//
#include <hip/hip_runtime.h>
#include <math.h>

// ---- problem constants ----
#define WAV_N     262144
#define HOP       128
#define MIN_WIN   16699
#define LEFT      24418            // (65536 - 16699)/2
#define T_FRAMES  2049
#define N_BINS    96
#define N_CQCC    20
#define F_COMP    192              // 96 bins x {lo,hi}
#define NF        576              // 192 comps x 3 Hann planes
#define NBLK      2179             // 128-sample chunks covering padded signal
#define NBP       2240             // padded b-dim for QFP rows (= 35*64)
#define PARTLEN   59               // 16699 - 130*128
#define FULLBLK   130
#define XS_VALID  278843           // 2048*128 + 16699
#define TWOPI     6.283185307179586f

// ---- chunk kernel tiling: 256 thr = 16 f-pairs x 16 b-groups(4 b each) ----
#define BT   64
#define FTW  32
#define JC   32
#define AST  68                    // A_lds row stride (272 B, 16B-aligned)

// ---- workspace layout (bytes) ----
#define WS_QFP  0                  // 576*2240*16 = 20,643,840  float4(qf.re,qf.im,qp.re,qp.im)
#define WS_SC   20643840           // 192*2056*8  =  3,158,016  folded spectrum [c][t]
#define WS_CQ   23801856           // 2049*20*4   =    163,920
#define WS_SUMS 23965776           // 40 doubles
#define SCP     2056               // Sc row stride (float2 units)

// f = plane*192 + c; c = bin*2 + hi; replicate reference f32 arithmetic for floor()
__device__ __forceinline__ void f_to_fi_sigma(int f, int& fi, int& sigma) {
    int plane = f / 192;
    int c = f - plane * 192;
    int bin = c >> 1, hi = c & 1;
    float e    = (float)bin / 24.0f;
    float fb   = 32.7f * exp2f(e);
    float idxf = fb / 8000.0f * 32768.0f;
    fi = (int)idxf + hi;
    sigma = (plane == 0) ? 0 : (plane == 1 ? 1 : -1);
}

// QFP[f][b] = (qf, qp): qf = e^{-i w0} sum_{j<128} xs[128b+j] E[j][f], qp = j<59 version
// E via register rotators re-anchored every 32 j; A staged in 32-j LDS chunks.
// 630 blocks (35 x 18) for occupancy: r5's 315-block FTW=64 variant ran 1 wave/SIMD
// (VALUBusy 20%) -- latency-bound, not issue-bound.
__global__ __launch_bounds__(256) void k_chunk(const float* __restrict__ wav,
                                               float4* __restrict__ QFP) {
    __shared__ float A_lds[JC * AST];              // 8704 B
    int tid = threadIdx.x;
    int b0 = blockIdx.x * BT;
    int f0 = blockIdx.y * FTW;
    int ftp = tid & 15;                            // f-pair index (32 f per block)
    int bg  = tid >> 4;                            // 16 groups x 4 b
    int bb  = b0 + bg * 4;

    int fi[2], sg[2];
    f_to_fi_sigma(f0 + 2 * ftp,     fi[0], sg[0]);
    f_to_fi_sigma(f0 + 2 * ftp + 1, fi[1], sg[1]);

    // per-j rotator step D[f] = e^{-2*pi*i*(fi/65536 - sg/W)}
    float Dr[2], Di[2];
    #pragma unroll
    for (int h = 0; h < 2; ++h) {
        float fr = (float)fi[h] * (1.0f / 65536.0f)
                 - (float)sg[h] * (1.0f / (float)MIN_WIN);
        fr -= rintf(fr);
        float sn, cs; __sincosf(TWOPI * fr, &sn, &cs);
        Dr[h] = cs; Di[h] = -sn;
    }

    float xr[2][4], xi[2][4], pr[2][4], pi[2][4];
    #pragma unroll
    for (int h = 0; h < 2; ++h)
        #pragma unroll
        for (int i = 0; i < 4; ++i) { xr[h][i] = 0.f; xi[h][i] = 0.f; }

    for (int jc = 0; jc < 4; ++jc) {
        int jbase = jc * JC;
        __syncthreads();
        // stage A chunk: A_lds[j][bl] = xs[128*(b0+bl) + jbase + j], reflect from wav
        #pragma unroll
        for (int i = 0; i < 8; ++i) {
            int m = i * 256 + tid;                 // 32j x 64bl
            int j = m & 31, bl = m >> 5;
            int s = 128 * (b0 + bl) + jbase + j;
            float v = 0.0f;
            if (s < XS_VALID) {
                int w = s - 8350;                  // s + LEFT - 32768
                if (w < 0) w = -w;
                if (w >= WAV_N) w = 2 * WAV_N - 2 - w;
                v = wav[w];
            }
            A_lds[j * AST + bl] = v;
        }
        __syncthreads();
        // anchor rotators at j = jbase (exact integer phase -- no drift across chunks)
        float Wr[2], Wi[2];
        #pragma unroll
        for (int h = 0; h < 2; ++h) {
            float fr = (float)((jbase * fi[h]) & 65535) * (1.0f / 65536.0f)
                     - (float)sg[h] * (float)jbase * (1.0f / (float)MIN_WIN);
            fr -= rintf(fr);
            float sn, cs; __sincosf(TWOPI * fr, &sn, &cs);
            Wr[h] = cs; Wi[h] = -sn;
        }
        #pragma unroll 8
        for (int j32 = 0; j32 < JC; ++j32) {
            if (jc == 1 && j32 == PARTLEN - 32) {  // snapshot partial sum (j<59)
                #pragma unroll
                for (int h = 0; h < 2; ++h)
                    #pragma unroll
                    for (int i = 0; i < 4; ++i) { pr[h][i] = xr[h][i]; pi[h][i] = xi[h][i]; }
            }
            float4 a = *(const float4*)&A_lds[j32 * AST + bg * 4];
            const float aa[4] = {a.x, a.y, a.z, a.w};
            #pragma unroll
            for (int h = 0; h < 2; ++h) {
                float wr = Wr[h], wi = Wi[h];
                #pragma unroll
                for (int i = 0; i < 4; ++i) {
                    xr[h][i] = fmaf(aa[i], wr, xr[h][i]);
                    xi[h][i] = fmaf(aa[i], wi, xi[h][i]);
                }
                Wr[h] = wr * Dr[h] - wi * Di[h];
                Wi[h] = wr * Di[h] + wi * Dr[h];
            }
        }
    }

    // apply e^{-i w0(b,f)} and store (qf, qp) interleaved; b>=NBLK lands in row pad
    #pragma unroll
    for (int h = 0; h < 2; ++h) {
        int f = f0 + 2 * ftp + h;
        float4* dst = QFP + (size_t)f * NBP + bb;
        #pragma unroll
        for (int i = 0; i < 4; ++i) {
            int b = bb + i;
            unsigned ph = ((unsigned)fi[h] * (unsigned)(LEFT + 128 * b)) & 65535u;
            float frf = (float)ph * (1.0f / 65536.0f)
                      - (float)sg[h] * (float)((128 * b) % MIN_WIN) * (1.0f / (float)MIN_WIN);
            frf -= rintf(frf);
            float sn, cs; __sincosf(TWOPI * frf, &sn, &cs);
            dst[i] = make_float4(xr[h][i] * cs + xi[h][i] * sn,
                                 xi[h][i] * cs - xr[h][i] * sn,
                                 pr[h][i] * cs + pi[h][i] * sn,
                                 pi[h][i] * cs - pr[h][i] * sn);
        }
    }
}

// one block per component c: scan 3 plane-columns (fp64), U = G[t+130]-G[t]+qp[t+130],
// rotate by e^{+i tau}, fold planes (0.5, -0.25, -0.25), write Sc[c][t]
#define SEG 9                      // 256*9 >= 2179
__global__ __launch_bounds__(256) void k_scan(const float4* __restrict__ QFP,
                                              float2* __restrict__ Sc,
                                              double* __restrict__ sums) {
    __shared__ float4 col[NBLK];       // 34,864 B
    __shared__ float2 acc[T_FRAMES];   // 16,392 B
    __shared__ double2 wsum[4];
    int tid = threadIdx.x;
    int c = blockIdx.x;
    if (c == 0 && tid < 40) sums[tid] = 0.0;   // zero stats accumulators

    for (int plane = 0; plane < 3; ++plane) {
        int f = plane * 192 + c;
        const float4* g = QFP + (size_t)f * NBP;
        #pragma unroll
        for (int k = 0; k < SEG; ++k) {
            int idx = k * 256 + tid;
            if (idx < NBLK) col[idx] = g[idx];
        }
        __syncthreads();
        int s0 = tid * SEG, s1 = min(s0 + SEG, NBLK);
        double sr = 0.0, si = 0.0;
        for (int i = s0; i < s1; ++i) { sr += col[i].x; si += col[i].y; }
        double r = sr, im = si;
        #pragma unroll
        for (int off = 1; off < 64; off <<= 1) {
            double prx = __shfl_up(r, off);
            double piy = __shfl_up(im, off);
            if ((tid & 63) >= off) { r += prx; im += piy; }
        }
        if ((tid & 63) == 63) wsum[tid >> 6] = make_double2(r, im);
        __syncthreads();
        double basr = 0.0, basi = 0.0;
        int w = tid >> 6;
        for (int ww = 0; ww < w; ++ww) { basr += wsum[ww].x; basi += wsum[ww].y; }
        double gr = basr + r - sr, gi = basi + im - si;   // exclusive prefix at s0
        for (int i = s0; i < s1; ++i) {
            float qx = col[i].x, qy = col[i].y;
            col[i].x = (float)gr; col[i].y = (float)gi;
            gr += qx; gi += qy;
        }
        __syncthreads();
        int fi_, sg_; f_to_fi_sigma(f, fi_, sg_);
        #pragma unroll
        for (int k = 0; k < SEG; ++k) {
            int t = k * 256 + tid;
            if (t < T_FRAMES) {
                float4 ca = col[t];
                float4 cb = col[t + FULLBLK];
                float ur = cb.x - ca.x + cb.z;
                float ui = cb.y - ca.y + cb.w;
                unsigned ph = ((unsigned)fi_ * 128u * (unsigned)t) & 65535u;
                float frf = (float)ph * (1.0f / 65536.0f)
                          - (float)sg_ * (float)((128 * t) % MIN_WIN) * (1.0f / (float)MIN_WIN);
                frf -= rintf(frf);
                float sn, cs;
                __sincosf(TWOPI * frf, &sn, &cs);
                float vr = ur * cs - ui * sn;
                float vi = ur * sn + ui * cs;
                if (plane == 0) acc[t] = make_float2(0.5f * vr, 0.5f * vi);
                else { acc[t].x -= 0.25f * vr; acc[t].y -= 0.25f * vi; }
            }
        }
        __syncthreads();
    }
    #pragma unroll
    for (int k = 0; k < SEG; ++k) {
        int t = k * 256 + tid;
        if (t < T_FRAMES) Sc[(size_t)c * SCP + t] = acc[t];
    }
}

// 8 frames/block: power -> interp -> log -> DCT; fp64 atomic stats partials
__global__ __launch_bounds__(256) void k_cqt(const float2* __restrict__ Sc,
                                             float* __restrict__ cq,
                                             double* __restrict__ sums) {
    __shared__ float dctm[N_CQCC * N_BINS];  // 7680 B
    __shared__ float lg[8][N_BINS];
    __shared__ float cqv[8][N_CQCC];
    int tid = threadIdx.x;
    int tb = blockIdx.x * 8;
    for (int idx = tid; idx < N_CQCC * N_BINS; idx += 256) {
        int k = idx / N_BINS, b = idx - k * N_BINS;
        dctm[idx] = cosf((float)M_PI * (float)(k * (2 * b + 1)) / 192.0f);
    }
    int lt = tid >> 5, lane = tid & 31;
    int t = tb + lt;
    #pragma unroll
    for (int bb = 0; bb < 3; ++bb) {
        int b = lane + 32 * bb;
        float lv = 0.0f;
        if (t < T_FRAMES) {
            float2 lo = Sc[(size_t)(2 * b) * SCP + t];
            float2 hi = Sc[(size_t)(2 * b + 1) * SCP + t];
            float pl = lo.x * lo.x + lo.y * lo.y;
            float ph = hi.x * hi.x + hi.y * hi.y;
            float e    = (float)b / 24.0f;
            float fb   = 32.7f * exp2f(e);
            float idxf = fb / 8000.0f * 32768.0f;
            float alpha = idxf - (float)((int)idxf);
            float p = (1.0f - alpha) * pl + alpha * ph;
            lv = logf(fmaxf(p, 1e-8f));
        }
        lg[lt][b] = lv;
    }
    __syncthreads();
    if (tid < 8 * N_CQCC) {
        int lt2 = tid / N_CQCC, k = tid - lt2 * N_CQCC;
        int t2 = tb + lt2;
        float s = 0.0f;
        #pragma unroll 4
        for (int b = 0; b < N_BINS; ++b) s += dctm[k * N_BINS + b] * lg[lt2][b];
        cqv[lt2][k] = (t2 < T_FRAMES) ? s : 0.0f;
        if (t2 < T_FRAMES) cq[t2 * N_CQCC + k] = s;
    }
    __syncthreads();
    if (tid < N_CQCC) {
        double s1 = 0.0, s2 = 0.0;
        #pragma unroll
        for (int lt2 = 0; lt2 < 8; ++lt2) {
            if (tb + lt2 < T_FRAMES) {
                double v = (double)cqv[lt2][tid];
                s1 += v; s2 += v * v;
            }
        }
        atomicAdd(&sums[tid], s1);
        atomicAdd(&sums[N_CQCC + tid], s2);
    }
}

__device__ __forceinline__ int clampT(int v) {
    return v < 0 ? 0 : (v > T_FRAMES - 1 ? T_FRAMES - 1 : v);
}

// normalize + delta + delta-delta; mean/inv derived inline from fp64 sums
__global__ void k_final(const float* __restrict__ cq, const double* __restrict__ sums,
                        float* __restrict__ out) {
    int gid = blockIdx.x * blockDim.x + threadIdx.x;
    if (gid >= T_FRAMES * N_CQCC) return;
    int t = gid / N_CQCC;
    int k = gid - t * N_CQCC;
    double S1 = sums[k], S2 = sums[N_CQCC + k];
    double md = S1 / (double)T_FRAMES;
    double var = (S2 - S1 * md) / (double)(T_FRAMES - 1);
    double sd = sqrt(var > 0.0 ? var : 0.0);
    float m = (float)md;
    float iv = (float)(1.0 / (sd + 1e-8));
    float cv[9];
    #pragma unroll
    for (int j = 0; j < 9; ++j)
        cv[j] = (cq[clampT(t + j - 4) * N_CQCC + k] - m) * iv;
    float dv[5];
    #pragma unroll
    for (int o = -2; o <= 2; ++o) {
        int p = clampT(t + o);
        int h1 = clampT(p + 1) - t, l1 = clampT(p - 1) - t;
        int h2 = clampT(p + 2) - t, l2 = clampT(p - 2) - t;
        dv[o + 2] = ((cv[h1 + 4] - cv[l1 + 4]) + 2.0f * (cv[h2 + 4] - cv[l2 + 4])) * 0.1f;
    }
    out[t * 60 + k]      = cv[4];
    out[t * 60 + 20 + k] = dv[2];
    out[t * 60 + 40 + k] = (dv[3] - dv[1] + 2.0f * (dv[4] - dv[0])) * 0.1f;
}

extern "C" void kernel_launch(void* const* d_in, const int* in_sizes, int n_in,
                              void* d_out, int out_size, void* d_ws, size_t ws_size,
                              hipStream_t stream) {
    const float* wav = (const float*)d_in[0];
    float* out = (float*)d_out;
    char* ws = (char*)d_ws;
    float4* QFP  = (float4*)(ws + WS_QFP);
    float2* Sc   = (float2*)(ws + WS_SC);
    float*  cq   = (float*)(ws + WS_CQ);
    double* sums = (double*)(ws + WS_SUMS);

    k_chunk<<<dim3(NBP / BT, NF / FTW), 256, 0, stream>>>(wav, QFP);
    k_scan<<<F_COMP, 256, 0, stream>>>(QFP, Sc, sums);
    k_cqt<<<(T_FRAMES + 7) / 8, 256, 0, stream>>>(Sc, cq, sums);
    k_final<<<(T_FRAMES * N_CQCC + 255) / 256, 256, 0, stream>>>(cq, sums, out);
}